// Round 1
// baseline (3385.906 us; speedup 1.0000x reference)
//
#include <hip/hip_runtime.h>

// GCN autoencoder: N=100000 nodes, E=1600000 edges, 512 -> 64 -> 512.
// Pipeline: degrees -> norms -> GEMM1 (feat@W1) -> scatter1 (atomics) ->
//           scatter2 (fused relu/norms, atomics) -> GEMM2 ((agg2*nd)@W2).
// Workspace use: 130*N floats = 52 MB.

// ---------------- degree / norm ----------------
__global__ void deg_kernel(const int* __restrict__ src, const int* __restrict__ dst,
                           float* __restrict__ degO, float* __restrict__ degI, int E) {
    int e = blockIdx.x * blockDim.x + threadIdx.x;
    if (e < E) {
        atomicAdd(&degO[src[e]], 1.0f);
        atomicAdd(&degI[dst[e]], 1.0f);
    }
}

__global__ void norm_kernel(float* __restrict__ degO, float* __restrict__ degI, int n) {
    int i = blockIdx.x * blockDim.x + threadIdx.x;
    if (i < n) {
        degO[i] = rsqrtf(fmaxf(degO[i], 1.0f));  // where(deg>0, deg, 1)^-0.5
        degI[i] = rsqrtf(fmaxf(degI[i], 1.0f));
    }
}

// ---------------- GEMM1: C[M x 64] = A[M x 512] @ B[512 x 64], fp32 ----------------
// BM=256, BN=64, BK=32; 256 threads; 8x8 register blocking per thread.
__launch_bounds__(256)
__global__ void gemm1_kernel(const float* __restrict__ A, const float* __restrict__ B,
                             float* __restrict__ C, int M) {
    __shared__ __align__(16) float As[32][260];  // transposed A tile, +4 pad
    __shared__ __align__(16) float Bs[32][64];
    const int tid = threadIdx.x;
    const int txn = tid & 7;    // col group: cols txn*8 .. txn*8+7
    const int tym = tid >> 3;   // row group: rows tym*8 .. tym*8+7 (0..31)
    const int rowBase = blockIdx.x * 256;

    float acc[8][8];
#pragma unroll
    for (int i = 0; i < 8; ++i)
#pragma unroll
        for (int j = 0; j < 8; ++j) acc[i][j] = 0.0f;

    for (int k0 = 0; k0 < 512; k0 += 32) {
        // stage A tile (256 rows x 32 k) transposed into LDS
#pragma unroll
        for (int p = 0; p < 8; ++p) {
            int idx = p * 256 + tid;
            int r  = idx >> 3;          // 0..255
            int kv = (idx & 7) * 4;     // 0,4,..,28
            int gr = rowBase + r;
            float4 v = make_float4(0.f, 0.f, 0.f, 0.f);
            if (gr < M) v = *(const float4*)(A + (size_t)gr * 512 + k0 + kv);
            As[kv + 0][r] = v.x; As[kv + 1][r] = v.y;
            As[kv + 2][r] = v.z; As[kv + 3][r] = v.w;
        }
        // stage B tile (32 k x 64 cols)
#pragma unroll
        for (int p = 0; p < 2; ++p) {
            int idx = p * 256 + tid;
            int kr = idx >> 4;          // 0..31
            int nv = (idx & 15) * 4;    // 0..60
            *(float4*)&Bs[kr][nv] = *(const float4*)(B + (size_t)(k0 + kr) * 64 + nv);
        }
        __syncthreads();

#pragma unroll 4
        for (int k = 0; k < 32; ++k) {
            float a[8], b[8];
            *(float4*)&a[0] = *(const float4*)&As[k][tym * 8];
            *(float4*)&a[4] = *(const float4*)&As[k][tym * 8 + 4];
            *(float4*)&b[0] = *(const float4*)&Bs[k][txn * 8];
            *(float4*)&b[4] = *(const float4*)&Bs[k][txn * 8 + 4];
#pragma unroll
            for (int i = 0; i < 8; ++i)
#pragma unroll
                for (int j = 0; j < 8; ++j)
                    acc[i][j] = fmaf(a[i], b[j], acc[i][j]);
        }
        __syncthreads();
    }

#pragma unroll
    for (int i = 0; i < 8; ++i) {
        int gr = rowBase + tym * 8 + i;
        if (gr < M) {
            *(float4*)(C + (size_t)gr * 64 + txn * 8) =
                make_float4(acc[i][0], acc[i][1], acc[i][2], acc[i][3]);
            *(float4*)(C + (size_t)gr * 64 + txn * 8 + 4) =
                make_float4(acc[i][4], acc[i][5], acc[i][6], acc[i][7]);
        }
    }
}

// ---------------- edge scatter: agg[dst] += msg(x[src]) ----------------
// 16 lanes per edge, float4 per lane (64 features). RELU variant fuses
// relu + dst-norm of layer-1 output into the layer-2 message.
template <bool RELU>
__global__ void scatter_kernel(const float* __restrict__ x, const int* __restrict__ src,
                               const int* __restrict__ dst, const float* __restrict__ ns,
                               const float* __restrict__ nd, float* __restrict__ agg, int E) {
    int t = blockIdx.x * blockDim.x + threadIdx.x;
    int e = t >> 4;
    if (e >= E) return;
    int l = (t & 15) * 4;
    int s = src[e];
    int d = dst[e];
    float sc = RELU ? ns[s] * nd[s] : ns[s];
    float4 v = *(const float4*)(x + (size_t)s * 64 + l);
    if (RELU) {
        v.x = fmaxf(v.x, 0.f); v.y = fmaxf(v.y, 0.f);
        v.z = fmaxf(v.z, 0.f); v.w = fmaxf(v.w, 0.f);
    }
    float* o = agg + (size_t)d * 64 + l;
    atomicAdd(o + 0, v.x * sc);
    atomicAdd(o + 1, v.y * sc);
    atomicAdd(o + 2, v.z * sc);
    atomicAdd(o + 3, v.w * sc);
}

// ---------------- GEMM2: C[M x 512] = (A[M x 64] * nd[row]) @ B[64 x 512] ----------------
// BM=128, BN=128, K=64 (single stage); 256 threads; 8x8 blocking.
__launch_bounds__(256)
__global__ void gemm2_kernel(const float* __restrict__ A, const float* __restrict__ nd,
                             const float* __restrict__ B, float* __restrict__ C, int M) {
    __shared__ __align__(16) float As[64][132];  // transposed A tile
    __shared__ __align__(16) float Bs[64][132];
    const int tid = threadIdx.x;
    const int txn = tid & 15;   // col group: cols {txn*4..+3, 64+txn*4..+3}
    const int tym = tid >> 4;   // row group: rows tym*8..+7 (0..15)
    const int rowBase = blockIdx.x * 128;
    const int colBase = blockIdx.y * 128;

    // stage A (128 rows x 64 k), fused row-scale by nd
#pragma unroll
    for (int p = 0; p < 8; ++p) {
        int idx = p * 256 + tid;
        int r  = idx >> 4;          // 0..127
        int kv = (idx & 15) * 4;    // 0..60
        int gr = rowBase + r;
        float4 v = make_float4(0.f, 0.f, 0.f, 0.f);
        if (gr < M) {
            v = *(const float4*)(A + (size_t)gr * 64 + kv);
            float s = nd[gr];
            v.x *= s; v.y *= s; v.z *= s; v.w *= s;
        }
        As[kv + 0][r] = v.x; As[kv + 1][r] = v.y;
        As[kv + 2][r] = v.z; As[kv + 3][r] = v.w;
    }
    // stage B (64 k x 128 cols)
#pragma unroll
    for (int p = 0; p < 8; ++p) {
        int idx = p * 256 + tid;
        int kr = idx >> 5;          // 0..63
        int nv = (idx & 31) * 4;    // 0..124
        *(float4*)&Bs[kr][nv] = *(const float4*)(B + (size_t)kr * 512 + colBase + nv);
    }
    __syncthreads();

    float acc[8][8];
#pragma unroll
    for (int i = 0; i < 8; ++i)
#pragma unroll
        for (int j = 0; j < 8; ++j) acc[i][j] = 0.0f;

#pragma unroll 4
    for (int k = 0; k < 64; ++k) {
        float a[8], b[8];
        *(float4*)&a[0] = *(const float4*)&As[k][tym * 8];
        *(float4*)&a[4] = *(const float4*)&As[k][tym * 8 + 4];
        *(float4*)&b[0] = *(const float4*)&Bs[k][txn * 4];        // cols txn*4..+3
        *(float4*)&b[4] = *(const float4*)&Bs[k][64 + txn * 4];   // cols 64+txn*4..+3
#pragma unroll
        for (int i = 0; i < 8; ++i)
#pragma unroll
            for (int j = 0; j < 8; ++j)
                acc[i][j] = fmaf(a[i], b[j], acc[i][j]);
    }

#pragma unroll
    for (int i = 0; i < 8; ++i) {
        int gr = rowBase + tym * 8 + i;
        if (gr < M) {
            *(float4*)(C + (size_t)gr * 512 + colBase + txn * 4) =
                make_float4(acc[i][0], acc[i][1], acc[i][2], acc[i][3]);
            *(float4*)(C + (size_t)gr * 512 + colBase + 64 + txn * 4) =
                make_float4(acc[i][4], acc[i][5], acc[i][6], acc[i][7]);
        }
    }
}

extern "C" void kernel_launch(void* const* d_in, const int* in_sizes, int n_in,
                              void* d_out, int out_size, void* d_ws, size_t ws_size,
                              hipStream_t stream) {
    const float* feat = (const float*)d_in[0];
    const int*   src  = (const int*)d_in[1];
    const int*   dst  = (const int*)d_in[2];
    const float* W1   = (const float*)d_in[3];
    const float* W2   = (const float*)d_in[4];
    const int N = in_sizes[0] / 512;  // 100000
    const int E = in_sizes[1];        // 1600000
    float* out = (float*)d_out;

    // workspace layout (floats): norm_src[N] | norm_dst[N] | buf1[64N] | agg1[64N]
    float* ws       = (float*)d_ws;
    float* norm_src = ws;
    float* norm_dst = ws + (size_t)N;
    float* buf1     = ws + 2 * (size_t)N;                 // h1, later reused as agg2
    float* agg1     = ws + 2 * (size_t)N + 64 * (size_t)N;

    hipMemsetAsync(norm_src, 0, 2 * (size_t)N * sizeof(float), stream);
    hipMemsetAsync(agg1, 0, 64 * (size_t)N * sizeof(float), stream);

    deg_kernel<<<(E + 255) / 256, 256, 0, stream>>>(src, dst, norm_src, norm_dst, E);
    norm_kernel<<<(N + 255) / 256, 256, 0, stream>>>(norm_src, norm_dst, N);

    // h1 = feat @ W1
    gemm1_kernel<<<(N + 255) / 256, 256, 0, stream>>>(feat, W1, buf1, N);

    // agg1[dst] += h1[src] * ns[src]
    scatter_kernel<false><<<(E * 16 + 255) / 256, 256, 0, stream>>>(
        buf1, src, dst, norm_src, norm_dst, agg1, E);

    // reuse buf1 as agg2
    hipMemsetAsync(buf1, 0, 64 * (size_t)N * sizeof(float), stream);

    // agg2[dst] += relu(agg1[src]) * nd[src] * ns[src]
    scatter_kernel<true><<<(E * 16 + 255) / 256, 256, 0, stream>>>(
        agg1, src, dst, norm_src, norm_dst, buf1, E);

    // out = (agg2 * nd[row]) @ W2
    gemm2_kernel<<<dim3((N + 127) / 128, 4), 256, 0, stream>>>(buf1, norm_dst, W2, out, N);
}

// Round 2
// 974.784 us; speedup vs baseline: 3.4735x; 3.4735x over previous
//
#include <hip/hip_runtime.h>

// GCN autoencoder: N=100000 nodes, E=1600000 edges, 512 -> 64 -> 512.
// R2: replace atomic scatter (1354us each, WRITE_SIZE 1.6GB) with dst-CSR
// gather (one wave per node, register accumulation, single write per row).
// Pipeline: deg -> norms -> scan(rowptr) -> fill CSR -> GEMM1 -> gather1 ->
//           gather2 (fused relu/norms) -> GEMM2 (fused dst-norm).

// ---------------- degree count ----------------
__global__ void deg_kernel(const int* __restrict__ src, const int* __restrict__ dst,
                           float* __restrict__ degO, int* __restrict__ cnt, int E) {
    int e = blockIdx.x * blockDim.x + threadIdx.x;
    if (e < E) {
        atomicAdd(&degO[src[e]], 1.0f);
        atomicAdd(&cnt[dst[e]], 1);
    }
}

// ns = rsqrt(max(deg_out,1)); nd = rsqrt(max(deg_in,1)); scale2 = ns*nd
__global__ void norm_kernel(float* __restrict__ ns, float* __restrict__ nd,
                            float* __restrict__ scale2, const int* __restrict__ cnt, int n) {
    int i = blockIdx.x * blockDim.x + threadIdx.x;
    if (i < n) {
        float a = rsqrtf(fmaxf(ns[i], 1.0f));
        float b = rsqrtf(fmaxf((float)cnt[i], 1.0f));
        ns[i] = a; nd[i] = b; scale2[i] = a * b;
    }
}

// ---------------- exclusive scan of cnt -> rowptr (3-phase) ----------------
__global__ void scan_pass1(const int* __restrict__ cnt, int* __restrict__ rowptr,
                           int* __restrict__ bsum, int n) {
    __shared__ int tmp[256];
    int tid = threadIdx.x;
    int i = blockIdx.x * 256 + tid;
    int v = (i < n) ? cnt[i] : 0;
    tmp[tid] = v;
    __syncthreads();
    for (int off = 1; off < 256; off <<= 1) {
        int t = (tid >= off) ? tmp[tid - off] : 0;
        __syncthreads();
        tmp[tid] += t;
        __syncthreads();
    }
    if (i < n) rowptr[i] = tmp[tid] - v;  // block-local exclusive
    if (tid == 255) bsum[blockIdx.x] = tmp[255];
}

__global__ void scan_pass2(int* __restrict__ bsum, int nb) {
    __shared__ int tmp[512];
    int tid = threadIdx.x;
    int v = (tid < nb) ? bsum[tid] : 0;
    tmp[tid] = v;
    __syncthreads();
    for (int off = 1; off < 512; off <<= 1) {
        int t = (tid >= off) ? tmp[tid - off] : 0;
        __syncthreads();
        tmp[tid] += t;
        __syncthreads();
    }
    if (tid < nb) bsum[tid] = tmp[tid] - v;  // exclusive block offsets
}

__global__ void scan_pass3(int* __restrict__ rowptr, int* __restrict__ cursor,
                           const int* __restrict__ bsum, int n, int E) {
    int i = blockIdx.x * 256 + threadIdx.x;
    if (i < n) {
        int v = rowptr[i] + bsum[blockIdx.x];
        rowptr[i] = v;
        cursor[i] = v;  // fill cursor starts at row base
    }
    if (i == 0) rowptr[n] = E;
}

// ---------------- CSR fill (order within a row is irrelevant) ----------------
__global__ void fill_csr(const int* __restrict__ src, const int* __restrict__ dst,
                         int* __restrict__ cursor, int* __restrict__ csr, int E) {
    int e = blockIdx.x * blockDim.x + threadIdx.x;
    if (e < E) {
        int p = atomicAdd(&cursor[dst[e]], 1);
        csr[p] = src[e];
    }
}

// ---------------- gather aggregation: one wave per node, lane = feature ----------------
// out[d][lane] = sum over in-edges of msg(x[s][lane]) * scale[s]
template <bool RELU>
__global__ void gather_kernel(const float* __restrict__ x, const int* __restrict__ rowptr,
                              const int* __restrict__ csr, const float* __restrict__ scale,
                              float* __restrict__ out, int N) {
    int node = blockIdx.x * 4 + (threadIdx.x >> 6);
    if (node >= N) return;
    int lane = threadIdx.x & 63;
    int beg = rowptr[node], end = rowptr[node + 1];
    float acc = 0.0f;
    int i = beg;
    for (; i + 1 < end; i += 2) {  // 2x unroll for MLP
        int s0 = csr[i], s1 = csr[i + 1];
        float sc0 = scale[s0], sc1 = scale[s1];
        float v0 = x[(size_t)s0 * 64 + lane];
        float v1 = x[(size_t)s1 * 64 + lane];
        if (RELU) { v0 = fmaxf(v0, 0.0f); v1 = fmaxf(v1, 0.0f); }
        acc = fmaf(v0, sc0, acc);
        acc = fmaf(v1, sc1, acc);
    }
    if (i < end) {
        int s = csr[i];
        float v = x[(size_t)s * 64 + lane];
        if (RELU) v = fmaxf(v, 0.0f);
        acc = fmaf(v, scale[s], acc);
    }
    out[(size_t)node * 64 + lane] = acc;
}

// ---------------- GEMM1: C[M x 64] = A[M x 512] @ B[512 x 64], fp32 ----------------
__launch_bounds__(256)
__global__ void gemm1_kernel(const float* __restrict__ A, const float* __restrict__ B,
                             float* __restrict__ C, int M) {
    __shared__ __align__(16) float As[32][260];
    __shared__ __align__(16) float Bs[32][64];
    const int tid = threadIdx.x;
    const int txn = tid & 7;
    const int tym = tid >> 3;
    const int rowBase = blockIdx.x * 256;

    float acc[8][8];
#pragma unroll
    for (int i = 0; i < 8; ++i)
#pragma unroll
        for (int j = 0; j < 8; ++j) acc[i][j] = 0.0f;

    for (int k0 = 0; k0 < 512; k0 += 32) {
#pragma unroll
        for (int p = 0; p < 8; ++p) {
            int idx = p * 256 + tid;
            int r  = idx >> 3;
            int kv = (idx & 7) * 4;
            int gr = rowBase + r;
            float4 v = make_float4(0.f, 0.f, 0.f, 0.f);
            if (gr < M) v = *(const float4*)(A + (size_t)gr * 512 + k0 + kv);
            As[kv + 0][r] = v.x; As[kv + 1][r] = v.y;
            As[kv + 2][r] = v.z; As[kv + 3][r] = v.w;
        }
#pragma unroll
        for (int p = 0; p < 2; ++p) {
            int idx = p * 256 + tid;
            int kr = idx >> 4;
            int nv = (idx & 15) * 4;
            *(float4*)&Bs[kr][nv] = *(const float4*)(B + (size_t)(k0 + kr) * 64 + nv);
        }
        __syncthreads();

#pragma unroll 4
        for (int k = 0; k < 32; ++k) {
            float a[8], b[8];
            *(float4*)&a[0] = *(const float4*)&As[k][tym * 8];
            *(float4*)&a[4] = *(const float4*)&As[k][tym * 8 + 4];
            *(float4*)&b[0] = *(const float4*)&Bs[k][txn * 8];
            *(float4*)&b[4] = *(const float4*)&Bs[k][txn * 8 + 4];
#pragma unroll
            for (int i = 0; i < 8; ++i)
#pragma unroll
                for (int j = 0; j < 8; ++j)
                    acc[i][j] = fmaf(a[i], b[j], acc[i][j]);
        }
        __syncthreads();
    }

#pragma unroll
    for (int i = 0; i < 8; ++i) {
        int gr = rowBase + tym * 8 + i;
        if (gr < M) {
            *(float4*)(C + (size_t)gr * 64 + txn * 8) =
                make_float4(acc[i][0], acc[i][1], acc[i][2], acc[i][3]);
            *(float4*)(C + (size_t)gr * 64 + txn * 8 + 4) =
                make_float4(acc[i][4], acc[i][5], acc[i][6], acc[i][7]);
        }
    }
}

// ---------------- GEMM2: C[M x 512] = (A[M x 64] * nd[row]) @ B[64 x 512] ----------------
__launch_bounds__(256)
__global__ void gemm2_kernel(const float* __restrict__ A, const float* __restrict__ nd,
                             const float* __restrict__ B, float* __restrict__ C, int M) {
    __shared__ __align__(16) float As[64][132];
    __shared__ __align__(16) float Bs[64][132];
    const int tid = threadIdx.x;
    const int txn = tid & 15;
    const int tym = tid >> 4;
    const int rowBase = blockIdx.x * 128;
    const int colBase = blockIdx.y * 128;

#pragma unroll
    for (int p = 0; p < 8; ++p) {
        int idx = p * 256 + tid;
        int r  = idx >> 4;
        int kv = (idx & 15) * 4;
        int gr = rowBase + r;
        float4 v = make_float4(0.f, 0.f, 0.f, 0.f);
        if (gr < M) {
            v = *(const float4*)(A + (size_t)gr * 64 + kv);
            float s = nd[gr];
            v.x *= s; v.y *= s; v.z *= s; v.w *= s;
        }
        As[kv + 0][r] = v.x; As[kv + 1][r] = v.y;
        As[kv + 2][r] = v.z; As[kv + 3][r] = v.w;
    }
#pragma unroll
    for (int p = 0; p < 8; ++p) {
        int idx = p * 256 + tid;
        int kr = idx >> 5;
        int nv = (idx & 31) * 4;
        *(float4*)&Bs[kr][nv] = *(const float4*)(B + (size_t)kr * 512 + colBase + nv);
    }
    __syncthreads();

    float acc[8][8];
#pragma unroll
    for (int i = 0; i < 8; ++i)
#pragma unroll
        for (int j = 0; j < 8; ++j) acc[i][j] = 0.0f;

#pragma unroll 4
    for (int k = 0; k < 64; ++k) {
        float a[8], b[8];
        *(float4*)&a[0] = *(const float4*)&As[k][tym * 8];
        *(float4*)&a[4] = *(const float4*)&As[k][tym * 8 + 4];
        *(float4*)&b[0] = *(const float4*)&Bs[k][txn * 4];
        *(float4*)&b[4] = *(const float4*)&Bs[k][64 + txn * 4];
#pragma unroll
        for (int i = 0; i < 8; ++i)
#pragma unroll
            for (int j = 0; j < 8; ++j)
                acc[i][j] = fmaf(a[i], b[j], acc[i][j]);
    }

#pragma unroll
    for (int i = 0; i < 8; ++i) {
        int gr = rowBase + tym * 8 + i;
        if (gr < M) {
            *(float4*)(C + (size_t)gr * 512 + colBase + txn * 4) =
                make_float4(acc[i][0], acc[i][1], acc[i][2], acc[i][3]);
            *(float4*)(C + (size_t)gr * 512 + colBase + 64 + txn * 4) =
                make_float4(acc[i][4], acc[i][5], acc[i][6], acc[i][7]);
        }
    }
}

extern "C" void kernel_launch(void* const* d_in, const int* in_sizes, int n_in,
                              void* d_out, int out_size, void* d_ws, size_t ws_size,
                              hipStream_t stream) {
    const float* feat = (const float*)d_in[0];
    const int*   src  = (const int*)d_in[1];
    const int*   dst  = (const int*)d_in[2];
    const float* W1   = (const float*)d_in[3];
    const float* W2   = (const float*)d_in[4];
    const int N = in_sizes[0] / 512;  // 100000
    const int E = in_sizes[1];        // 1600000
    float* out = (float*)d_out;

    // workspace layout
    float* ns     = (float*)d_ws;            // [N] (also degO accumulator)
    float* nd     = ns + N;                  // [N]
    float* scale2 = nd + N;                  // [N] = ns*nd
    int*   cnt    = (int*)(scale2 + N);      // [N] in-degree
    int*   rowptr = cnt + N;                 // [N+1]
    int*   cursor = rowptr + (N + 1);        // [N]
    int*   bsum   = cursor + N;              // [512]
    int*   csr    = bsum + 512;              // [E]
    float* buf1   = (float*)(((unsigned long long)(csr + E) + 15ull) & ~15ull); // [64N]
    float* agg1   = buf1 + (size_t)64 * N;   // [64N]

    hipMemsetAsync(ns, 0, (size_t)N * sizeof(float), stream);
    hipMemsetAsync(cnt, 0, (size_t)N * sizeof(int), stream);

    deg_kernel<<<(E + 255) / 256, 256, 0, stream>>>(src, dst, ns, cnt, E);
    norm_kernel<<<(N + 255) / 256, 256, 0, stream>>>(ns, nd, scale2, cnt, N);

    const int nb = (N + 255) / 256;  // 391 <= 512
    scan_pass1<<<nb, 256, 0, stream>>>(cnt, rowptr, bsum, N);
    scan_pass2<<<1, 512, 0, stream>>>(bsum, nb);
    scan_pass3<<<nb, 256, 0, stream>>>(rowptr, cursor, bsum, N, E);
    fill_csr<<<(E + 255) / 256, 256, 0, stream>>>(src, dst, cursor, csr, E);

    // h1 = feat @ W1
    gemm1_kernel<<<(N + 255) / 256, 256, 0, stream>>>(feat, W1, buf1, N);

    // agg1[d] = sum h1[s]*ns[s]
    gather_kernel<false><<<(N + 3) / 4, 256, 0, stream>>>(buf1, rowptr, csr, ns, agg1, N);

    // agg2[d] = sum relu(agg1[s])*ns[s]*nd[s]   (reuse buf1 as agg2)
    gather_kernel<true><<<(N + 3) / 4, 256, 0, stream>>>(agg1, rowptr, csr, scale2, buf1, N);

    // out = (agg2 * nd[row]) @ W2
    gemm2_kernel<<<dim3((N + 127) / 128, 4), 256, 0, stream>>>(buf1, nd, W2, out, N);
}